// Round 6
// baseline (302.509 us; speedup 1.0000x reference)
//
#include <hip/hip_runtime.h>

#define N_NODES 100000
#define N_EDGES 800000

typedef unsigned short u16;
typedef unsigned int u32;
typedef __attribute__((ext_vector_type(8))) short short8;
typedef __attribute__((ext_vector_type(4))) float floatx4;

#define NBUK 196            // ceil(100000 / 512)
#define BSH 9               // bucket = node >> 9  (512 nodes/bucket)
#define NBLK 512            // edge-partition blocks (contiguous ranges)
#define NE4 (N_EDGES / 4)   // 200000 int4 packets
#define CE 391              // ceil(NE4 / NBLK) int4 packets per block
#define NB_PREPW 192

__device__ __forceinline__ float bflo(u32 u) {
    union { u32 i; float f; } v; v.i = u << 16; return v.f;
}
__device__ __forceinline__ float bfhi(u32 u) {
    union { u32 i; float f; } v; v.i = u & 0xFFFF0000u; return v.f;
}
__device__ __forceinline__ u16 f2bf(float f) {
    union { float f; u32 i; } v; v.f = f;
    u32 r = (v.i + 0x7FFFu + ((v.i >> 16) & 1u)) >> 16;
    return (u16)r;
}
__device__ __forceinline__ float fast_tanh(float x) {
    float e = __expf(2.0f * x);
    return 1.0f - 2.0f * __builtin_amdgcn_rcpf(e + 1.0f);
}

// ---------------- phase A1: per-block bucket histograms (LDS atomics only) + weight prep ----------------
// frag layout [m][ot][ks][lane][j]: ot=o>>4, ks=k>>5, quad=(k>>3)&3, j=k&7, lane=(quad<<4)|(o&15)

__global__ __launch_bounds__(256) void kA_count(const int* __restrict__ src, const int* __restrict__ dst,
                                                int* __restrict__ countsD, int* __restrict__ countsS,
                                                const float* __restrict__ w1, const float* __restrict__ w2,
                                                const float* __restrict__ v, u16* __restrict__ wvfrag) {
    __shared__ int cd[NBUK], cs[NBUK];
    if (blockIdx.x >= NBLK) {   // weight-frag prep blocks
        int idx = (blockIdx.x - NBLK) * 256 + threadIdx.x;   // 3*16384
        if (idx < 3 * 16384) {
            int m = idx >> 14, r = idx & 16383;
            int k = r >> 7, o = r & 127;
            float val = (m == 0) ? w1[k * 128 + o] : (m == 1) ? w2[k * 128 + o] : v[k * 128 + o];
            int ot = o >> 4, ks = k >> 5, quad = (k >> 3) & 3, j = k & 7;
            int lane = (quad << 4) | (o & 15);
            wvfrag[(((m * 8 + ot) * 4 + ks) * 64 + lane) * 8 + j] = f2bf(val);
        }
        return;
    }
    for (int i = threadIdx.x; i < NBUK; i += 256) { cd[i] = 0; cs[i] = 0; }
    __syncthreads();
    int i0 = blockIdx.x * CE;
    int i1 = i0 + CE; if (i1 > NE4) i1 = NE4;
    for (int i = i0 + threadIdx.x; i < i1; i += 256) {
        int4 d4 = ((const int4*)dst)[i];
        int4 s4 = ((const int4*)src)[i];
        atomicAdd(&cd[d4.x >> BSH], 1); atomicAdd(&cd[d4.y >> BSH], 1);
        atomicAdd(&cd[d4.z >> BSH], 1); atomicAdd(&cd[d4.w >> BSH], 1);
        atomicAdd(&cs[s4.x >> BSH], 1); atomicAdd(&cs[s4.y >> BSH], 1);
        atomicAdd(&cs[s4.z >> BSH], 1); atomicAdd(&cs[s4.w >> BSH], 1);
    }
    __syncthreads();
    for (int i = threadIdx.x; i < NBUK; i += 256) {
        countsD[i * NBLK + blockIdx.x] = cd[i];
        countsS[i * NBLK + blockIdx.x] = cs[i];
    }
}

// ---------------- phase A2: per-bucket exclusive scan over blocks (in-place) + bucket totals ----------------

__global__ __launch_bounds__(256) void kA_scan(int* __restrict__ countsD, int* __restrict__ countsS,
                                               int* __restrict__ totD, int* __restrict__ totS) {
    __shared__ int sc[256];
    int b = blockIdx.x;
    int* cnt = (b < NBUK) ? (countsD + b * NBLK) : (countsS + (b - NBUK) * NBLK);
    int t = threadIdx.x;
    int v0 = cnt[2 * t], v1 = cnt[2 * t + 1];
    int s = v0 + v1;
    sc[t] = s; __syncthreads();
    for (int off = 1; off < 256; off <<= 1) {
        int x = (t >= off) ? sc[t - off] : 0;
        __syncthreads();
        sc[t] += x;
        __syncthreads();
    }
    int excl = sc[t] - s;   // exclusive
    cnt[2 * t] = excl; cnt[2 * t + 1] = excl + v0;
    if (t == 255) { if (b < NBUK) totD[b] = sc[255]; else totS[b - NBUK] = sc[255]; }
}

// ---------------- phase A3: bucket-partition edges (LDS cursors; bases computed inline) ----------------

__global__ __launch_bounds__(256) void kA_scatter(const int* __restrict__ src, const int* __restrict__ dst,
                                                  const int* __restrict__ attr,
                                                  const int* __restrict__ countsD, const int* __restrict__ countsS,
                                                  const int* __restrict__ totD, const int* __restrict__ totS,
                                                  uint2* __restrict__ dbuf, int* __restrict__ sbuf) {
    __shared__ int curD[NBUK], curS[NBUK];
    __shared__ int sd[256], ss[256];
    int t = threadIdx.x;
    int vd = (t < NBUK) ? totD[t] : 0;
    int vs = (t < NBUK) ? totS[t] : 0;
    sd[t] = vd; ss[t] = vs; __syncthreads();
    for (int off = 1; off < 256; off <<= 1) {
        int xd = (t >= off) ? sd[t - off] : 0;
        int xs = (t >= off) ? ss[t - off] : 0;
        __syncthreads();
        sd[t] += xd; ss[t] += xs;
        __syncthreads();
    }
    if (t < NBUK) {
        curD[t] = (sd[t] - vd) + countsD[t * NBLK + blockIdx.x];
        curS[t] = (ss[t] - vs) + countsS[t * NBLK + blockIdx.x];
    }
    __syncthreads();
    int i0 = blockIdx.x * CE;
    int i1 = i0 + CE; if (i1 > NE4) i1 = NE4;
    for (int i = i0 + t; i < i1; i += 256) {
        int4 s4 = ((const int4*)src)[i];
        int4 d4 = ((const int4*)dst)[i];
        int4 a4 = ((const int4*)attr)[i];
        int p, d, s, a;
        d = d4.x; s = s4.x; a = a4.x;
        p = atomicAdd(&curD[d >> BSH], 1); dbuf[p] = make_uint2((u32)d, (u32)((s << 5) | a));
        p = atomicAdd(&curS[s >> BSH], 1); sbuf[p] = s;
        d = d4.y; s = s4.y; a = a4.y;
        p = atomicAdd(&curD[d >> BSH], 1); dbuf[p] = make_uint2((u32)d, (u32)((s << 5) | a));
        p = atomicAdd(&curS[s >> BSH], 1); sbuf[p] = s;
        d = d4.z; s = s4.z; a = a4.z;
        p = atomicAdd(&curD[d >> BSH], 1); dbuf[p] = make_uint2((u32)d, (u32)((s << 5) | a));
        p = atomicAdd(&curS[s >> BSH], 1); sbuf[p] = s;
        d = d4.w; s = s4.w; a = a4.w;
        p = atomicAdd(&curD[d >> BSH], 1); dbuf[p] = make_uint2((u32)d, (u32)((s << 5) | a));
        p = atomicAdd(&curS[s >> BSH], 1); sbuf[p] = s;
    }
}

// ---------------- phase B: per-bucket node counts + rank + CSR emit (all LDS) ----------------
// blocks [0,NBUK): dst path (in_deg/in_scale/csr_start/csr_edge); [NBUK,2*NBUK): src path (out_scale)

__global__ __launch_bounds__(256) void k_build(const uint2* __restrict__ dbuf, const int* __restrict__ sbuf,
                                               const int* __restrict__ totD, const int* __restrict__ totS,
                                               int* __restrict__ csr_start, int* __restrict__ in_deg,
                                               float* __restrict__ in_scale, float* __restrict__ out_scale,
                                               int* __restrict__ csr_edge) {
    __shared__ int cnt[512];
    __shared__ int aux[512];
    __shared__ int sc[256];
    __shared__ int sbase;
    int t = threadIdx.x;
    int isS = blockIdx.x >= NBUK;
    int b = isS ? (blockIdx.x - NBUK) : blockIdx.x;
    const int* tot = isS ? totS : totD;
    if (t < 64) {   // exclusive prefix of tot[0..b)
        int s = 0;
        for (int i = t; i < b; i += 64) s += tot[i];
#pragma unroll
        for (int o = 32; o > 0; o >>= 1) s += __shfl_down(s, o);
        if (t == 0) sbase = s;
    }
    for (int i = t; i < 512; i += 256) cnt[i] = 0;
    __syncthreads();
    int st = sbase, n = tot[b];
    int nb0 = b << BSH;
    if (isS) {
        for (int i = st + t; i < st + n; i += 256) atomicAdd(&cnt[sbuf[i] - nb0], 1);
        __syncthreads();
        for (int s2 = t; s2 < 512; s2 += 256) {
            int node = nb0 + s2;
            if (node < N_NODES) { int c = cnt[s2]; if (c < 1) c = 1; out_scale[node] = rsqrtf((float)c); }
        }
        return;
    }
    for (int i = st + t; i < st + n; i += 256) { uint2 r = dbuf[i]; atomicAdd(&cnt[(int)r.x - nb0], 1); }
    __syncthreads();
    int c0 = cnt[2 * t], c1 = cnt[2 * t + 1];
    int s = c0 + c1; sc[t] = s; __syncthreads();
    for (int off = 1; off < 256; off <<= 1) {
        int x = (t >= off) ? sc[t - off] : 0;
        __syncthreads();
        sc[t] += x;
        __syncthreads();
    }
    int excl = sc[t] - s;
    aux[2 * t] = excl; aux[2 * t + 1] = excl + c0;
    int na = nb0 + 2 * t, nbv = nb0 + 2 * t + 1;
    if (na < N_NODES) {
        in_deg[na] = c0; int cc = c0 < 1 ? 1 : c0;
        in_scale[na] = rsqrtf((float)cc); csr_start[na] = st + excl;
    }
    if (nbv < N_NODES) {
        in_deg[nbv] = c1; int cc = c1 < 1 ? 1 : c1;
        in_scale[nbv] = rsqrtf((float)cc); csr_start[nbv] = st + excl + c0;
    }
    __syncthreads();
    for (int i = st + t; i < st + n; i += 256) {
        uint2 r = dbuf[i];
        int pos = atomicAdd(&aux[(int)r.x - nb0], 1);
        csr_edge[st + pos] = (int)r.y;
    }
}

// ---------------- fused node GEMMs, NO LDS: B-frags streamed from global (L1/L2-resident 64 KB) ----------------
// LDS=0 lifts occupancy from 2 -> ~6-7 waves/SIMD; kernel should approach its 102 MB HBM floor.
// hrow layout (256 u16 per node): u16 idx 2o = h_sum(o), 2o+1 = h_prod(o)  -> one u32 per (node,o)

__global__ __launch_bounds__(256) void k_gemm(const float* __restrict__ feat,
                                              const float* __restrict__ out_scale,
                                              const u16* __restrict__ wvfrag,
                                              const float* __restrict__ w2,
                                              u16* __restrict__ hrow) {
    int wave = threadIdx.x >> 6, lane = threadIdx.x & 63;
    int quad = lane >> 4, l15 = lane & 15;
    const float* bias = w2 + 128 * 128;
    float bias_v[8];
#pragma unroll
    for (int ot = 0; ot < 8; ot++) bias_v[ot] = bias[ot * 16 + l15];
    const short8* wv = (const short8*)wvfrag;   // frag idx = ((m*8+ot)*4+ks)*64 + lane
    int nb = blockIdx.x * 64 + wave * 16;
    int anode = nb + l15; if (anode >= N_NODES) anode = N_NODES - 1;
    float s = out_scale[anode];
    short8 a[4];
#pragma unroll
    for (int ks = 0; ks < 4; ks++) {
        float4 f0 = *(const float4*)(feat + anode * 128 + ks * 32 + quad * 8);
        float4 f1 = *(const float4*)(feat + anode * 128 + ks * 32 + quad * 8 + 4);
        short8 av;
        av[0] = (short)f2bf(f0.x * s); av[1] = (short)f2bf(f0.y * s);
        av[2] = (short)f2bf(f0.z * s); av[3] = (short)f2bf(f0.w * s);
        av[4] = (short)f2bf(f1.x * s); av[5] = (short)f2bf(f1.y * s);
        av[6] = (short)f2bf(f1.z * s); av[7] = (short)f2bf(f1.w * s);
        a[ks] = av;
    }
#pragma unroll
    for (int ot = 0; ot < 8; ot++) {
        floatx4 accS = (floatx4){0.f, 0.f, 0.f, 0.f};
        floatx4 accP = (floatx4){0.f, 0.f, 0.f, 0.f};
#pragma unroll
        for (int ks = 0; ks < 4; ks++) {
            short8 b0 = wv[(ot * 4 + ks) * 64 + lane];
            short8 b1 = wv[((8 + ot) * 4 + ks) * 64 + lane];
            accS = __builtin_amdgcn_mfma_f32_16x16x32_bf16(a[ks], b0, accS, 0, 0, 0);
            accP = __builtin_amdgcn_mfma_f32_16x16x32_bf16(a[ks], b1, accP, 0, 0, 0);
        }
        int o = ot * 16 + l15;
#pragma unroll
        for (int r = 0; r < 4; r++) {
            int node = nb + quad * 4 + r;
            if (node < N_NODES) {
                u32 pv = (u32)f2bf(accS[r]) | ((u32)f2bf(fast_tanh(accP[r] + bias_v[ot])) << 16);
                *(u32*)(hrow + node * 256 + o * 2) = pv;  // coalesced: 16 lanes -> 64 B line
            }
        }
    }
}

// ---------------- edge stage: guarded dual-stream DEPTH-3 pipeline + edge-balanced wave ranges ----------------
// bond back to global (proven best). Each wave binary-searches csr_start for an equal-EDGE pair
// range (~98 edges/wave), killing the static-striding straggler tail.
// hrow uint2 per lane: .x = {sum(2l) | prod(2l)<<16}, .y = {sum(2l+1) | prod(2l+1)<<16}

__device__ __forceinline__ int pair_lb(const int* __restrict__ csr_start, long long tgt) {
    const int NPAIR = N_NODES / 2;
    int lo = 0, hi = NPAIR;           // largest p in [0,NPAIR] with value(p) <= tgt; value(NPAIR)=N_EDGES
    while (lo < hi) {
        int mid = (lo + hi + 1) >> 1;
        int v = (mid == NPAIR) ? N_EDGES : csr_start[2 * mid];
        if (v <= tgt) lo = mid; else hi = mid - 1;
    }
    return lo;
}

__global__ __launch_bounds__(256, 8) void k_edge(const int* __restrict__ csr_start, const int* __restrict__ in_deg,
                                                 const int* __restrict__ csr_edge,
                                                 const u16* __restrict__ hrow,
                                                 const float* __restrict__ bond_emb,
                                                 float* __restrict__ out_hs, u16* __restrict__ hp) {
    int wid = (blockIdx.x * 256 + threadIdx.x) >> 6;
    int lane = threadIdx.x & 63;
    int nwaves = (gridDim.x * 256) >> 6;
    long long t0 = ((long long)wid * N_EDGES) / nwaves;
    long long t1 = ((long long)(wid + 1) * N_EDGES) / nwaves;
    int p0 = pair_lb(csr_start, t0);
    int p1 = pair_lb(csr_start, t1);
    uint2 hD0 = {0, 0}, hD1 = {0, 0};
    float2 eD0 = {0.f, 0.f}, eD1 = {0.f, 0.f};
    for (int pr = p0; pr < p1; pr++) {
        int n0 = pr * 2, n1 = n0 + 1;
        int st0 = csr_start[n0];
        int2 dd = *(const int2*)(in_deg + n0);     // n0 even -> 8B aligned
        int d0 = dd.x, d1 = dd.y;
        int st1 = st0 + d0;                         // CSR prefix property
        float as0 = 0.f, as1 = 0.f, ap0 = 1.f, ap1 = 1.f;
        float bs0 = 0.f, bs1 = 0.f, bp0 = 1.f, bp1 = 1.f;
        int b0 = 0, b1 = 0;
        while (b0 < d0 || b1 < d1) {
            int c0 = d0 - b0; c0 = c0 < 0 ? 0 : (c0 > 64 ? 64 : c0);
            int c1 = d1 - b1; c1 = c1 < 0 ? 0 : (c1 > 64 ? 64 : c1);
            int pkv0 = 0, pkv1 = 0;
            if (c0 > 0) { int li = lane < c0 ? lane : c0 - 1; pkv0 = csr_edge[st0 + b0 + li]; }
            if (c1 > 0) { int li = lane < c1 ? lane : c1 - 1; pkv1 = csr_edge[st1 + b1 + li]; }
            uint2 hA0 = hD0, hB0 = hD0, hC0 = hD0, hA1 = hD1, hB1 = hD1, hC1 = hD1;
            float2 eA0 = eD0, eB0 = eD0, eC0 = eD0, eA1 = eD1, eB1 = eD1, eC1 = eD1;
            if (c0 > 0) {
                int pk = __builtin_amdgcn_readlane(pkv0, 0);
                hA0 = *(const uint2*)(hrow + (pk >> 5) * 256 + 4 * lane);
                eA0 = *(const float2*)(bond_emb + (pk & 31) * 128 + 2 * lane);
                if (c0 > 1) {
                    pk = __builtin_amdgcn_readlane(pkv0, 1);
                    hB0 = *(const uint2*)(hrow + (pk >> 5) * 256 + 4 * lane);
                    eB0 = *(const float2*)(bond_emb + (pk & 31) * 128 + 2 * lane);
                    if (c0 > 2) {
                        pk = __builtin_amdgcn_readlane(pkv0, 2);
                        hC0 = *(const uint2*)(hrow + (pk >> 5) * 256 + 4 * lane);
                        eC0 = *(const float2*)(bond_emb + (pk & 31) * 128 + 2 * lane);
                    }
                }
            }
            if (c1 > 0) {
                int pk = __builtin_amdgcn_readlane(pkv1, 0);
                hA1 = *(const uint2*)(hrow + (pk >> 5) * 256 + 4 * lane);
                eA1 = *(const float2*)(bond_emb + (pk & 31) * 128 + 2 * lane);
                if (c1 > 1) {
                    pk = __builtin_amdgcn_readlane(pkv1, 1);
                    hB1 = *(const uint2*)(hrow + (pk >> 5) * 256 + 4 * lane);
                    eB1 = *(const float2*)(bond_emb + (pk & 31) * 128 + 2 * lane);
                    if (c1 > 2) {
                        pk = __builtin_amdgcn_readlane(pkv1, 2);
                        hC1 = *(const uint2*)(hrow + (pk >> 5) * 256 + 4 * lane);
                        eC1 = *(const float2*)(bond_emb + (pk & 31) * 128 + 2 * lane);
                    }
                }
            }
            int cm = c0 > c1 ? c0 : c1;
            for (int j = 0; j < cm; j++) {
                int jn = j + 3;
                if (jn < c0) {   // jn <= 63 guaranteed by jn < c0 <= 64
                    int pk = __builtin_amdgcn_readlane(pkv0, jn);
                    hD0 = *(const uint2*)(hrow + (pk >> 5) * 256 + 4 * lane);
                    eD0 = *(const float2*)(bond_emb + (pk & 31) * 128 + 2 * lane);
                }
                if (jn < c1) {
                    int pk = __builtin_amdgcn_readlane(pkv1, jn);
                    hD1 = *(const uint2*)(hrow + (pk >> 5) * 256 + 4 * lane);
                    eD1 = *(const float2*)(bond_emb + (pk & 31) * 128 + 2 * lane);
                }
                if (j < c0) {
                    as0 += bflo(hA0.x) * eA0.x;
                    ap0 *= bfhi(hA0.x) * eA0.x;
                    as1 += bflo(hA0.y) * eA0.y;
                    ap1 *= bfhi(hA0.y) * eA0.y;
                    hA0 = hB0; eA0 = eB0; hB0 = hC0; eB0 = eC0; hC0 = hD0; eC0 = eD0;
                }
                if (j < c1) {
                    bs0 += bflo(hA1.x) * eA1.x;
                    bp0 *= bfhi(hA1.x) * eA1.x;
                    bs1 += bflo(hA1.y) * eA1.y;
                    bp1 *= bfhi(hA1.y) * eA1.y;
                    hA1 = hB1; eA1 = eB1; hB1 = hC1; eB1 = eC1; hC1 = hD1; eC1 = eD1;
                }
            }
            b0 += 64; b1 += 64;
        }
        float2 sv0; sv0.x = as0; sv0.y = as1;
        float2 sv1; sv1.x = bs0; sv1.y = bs1;
        *(float2*)(out_hs + n0 * 128 + 2 * lane) = sv0;
        *(float2*)(out_hs + n1 * 128 + 2 * lane) = sv1;
        *(u32*)(hp + n0 * 128 + 2 * lane) = ((u32)f2bf(ap1) << 16) | (u32)f2bf(ap0);
        *(u32*)(hp + n1 * 128 + 2 * lane) = ((u32)f2bf(bp1) << 16) | (u32)f2bf(bp0);
    }
}

// ---------------- final: out = (hs + hp@v) * in_scale ; hs lives in d_out ----------------

__global__ __launch_bounds__(256) void k_final(const u16* __restrict__ hp,
                                               const u16* __restrict__ vfrag,
                                               const float* __restrict__ in_scale,
                                               float* __restrict__ out) {
    __shared__ u16 ldsw[16384];  // 32 KB
    for (int i = threadIdx.x; i < 2048; i += 256)
        ((ulonglong2*)ldsw)[i] = ((const ulonglong2*)vfrag)[i];
    __syncthreads();
    int wave = threadIdx.x >> 6, lane = threadIdx.x & 63;
    int quad = lane >> 4, l15 = lane & 15;
    const int NT = (N_NODES + 63) / 64;
    for (int tile = blockIdx.x; tile < NT; tile += gridDim.x) {
        int nb = tile * 64 + wave * 16;
        int anode = nb + l15; if (anode >= N_NODES) anode = N_NODES - 1;
        short8 a[4];
#pragma unroll
        for (int ks = 0; ks < 4; ks++)
            a[ks] = *(const short8*)(hp + anode * 128 + ks * 32 + quad * 8);
#pragma unroll
        for (int ot = 0; ot < 8; ot++) {
            floatx4 acc = (floatx4){0.f, 0.f, 0.f, 0.f};
#pragma unroll
            for (int ks = 0; ks < 4; ks++) {
                short8 b = *(const short8*)&ldsw[((ot * 4 + ks) * 64 + lane) * 8];
                acc = __builtin_amdgcn_mfma_f32_16x16x32_bf16(a[ks], b, acc, 0, 0, 0);
            }
            int o = ot * 16 + l15;
#pragma unroll
            for (int r = 0; r < 4; r++) {
                int node = nb + quad * 4 + r;
                if (node < N_NODES) {
                    float scl = in_scale[node];
                    float hsv = out[node * 128 + o];          // hs, written by k_edge
                    out[node * 128 + o] = (acc[r] + hsv) * scl;
                }
            }
        }
    }
}

extern "C" void kernel_launch(void* const* d_in, const int* in_sizes, int n_in,
                              void* d_out, int out_size, void* d_ws, size_t ws_size,
                              hipStream_t stream) {
    const float* feat = (const float*)d_in[0];
    const int* src = (const int*)d_in[1];
    const int* dst = (const int*)d_in[2];
    const int* attr = (const int*)d_in[3];
    const float* w1 = (const float*)d_in[4];
    const float* w2 = (const float*)d_in[5];
    const float* v = (const float*)d_in[6];
    const float* bond = (const float*)d_in[7];
    float* out = (float*)d_out;

    char* ws = (char*)d_ws;
    size_t off = 0;
    auto alloc = [&](size_t bytes) -> char* {
        char* p = ws + off; off += (bytes + 255) & ~(size_t)255; return p;
    };
    int* countsD   = (int*)alloc((size_t)NBUK * NBLK * 4);
    int* countsS   = (int*)alloc((size_t)NBUK * NBLK * 4);
    int* totD      = (int*)alloc((size_t)NBUK * 4);
    int* totS      = (int*)alloc((size_t)NBUK * 4);
    uint2* dbuf    = (uint2*)alloc((size_t)N_EDGES * 8);
    int* sbuf      = (int*)alloc((size_t)N_EDGES * 4);
    int* csr_start = (int*)alloc((size_t)N_NODES * 4);
    int* in_deg    = (int*)alloc((size_t)N_NODES * 4);
    float* out_scale = (float*)alloc((size_t)N_NODES * 4);
    float* in_scale  = (float*)alloc((size_t)N_NODES * 4);
    int* csr_edge  = (int*)alloc((size_t)N_EDGES * 4);
    u16* wvfrag = (u16*)alloc((size_t)3 * 16384 * 2);         // w1|w2|v bf16 frags
    u16* hrow   = (u16*)alloc((size_t)N_NODES * 256 * 2);     // [sum|prod] per channel
    u16* hp     = (u16*)alloc((size_t)N_NODES * 128 * 2);

    (void)in_sizes; (void)n_in; (void)out_size; (void)ws_size;

    kA_count<<<NBLK + NB_PREPW, 256, 0, stream>>>(src, dst, countsD, countsS, w1, w2, v, wvfrag);
    kA_scan<<<2 * NBUK, 256, 0, stream>>>(countsD, countsS, totD, totS);
    kA_scatter<<<NBLK, 256, 0, stream>>>(src, dst, attr, countsD, countsS, totD, totS, dbuf, sbuf);
    k_build<<<2 * NBUK, 256, 0, stream>>>(dbuf, sbuf, totD, totS,
                                          csr_start, in_deg, in_scale, out_scale, csr_edge);
    k_gemm<<<(N_NODES + 63) / 64, 256, 0, stream>>>(feat, out_scale, wvfrag, w2, hrow);
    k_edge<<<2048, 256, 0, stream>>>(csr_start, in_deg, csr_edge, hrow, bond, out, hp);
    k_final<<<1280, 256, 0, stream>>>(hp, wvfrag + 2 * 16384, in_scale, out);
}

// Round 7
// 268.764 us; speedup vs baseline: 1.1256x; 1.1256x over previous
//
#include <hip/hip_runtime.h>

#define N_NODES 100000
#define N_EDGES 800000

typedef unsigned short u16;
typedef unsigned int u32;
typedef __attribute__((ext_vector_type(8))) short short8;
typedef __attribute__((ext_vector_type(4))) float floatx4;

#define NBUK 196            // ceil(100000 / 512)
#define BSH 9               // bucket = node >> 9  (512 nodes/bucket)
#define NBLK 512            // edge-partition blocks (contiguous ranges)
#define NE4 (N_EDGES / 4)   // 200000 int4 packets
#define CE 391              // ceil(NE4 / NBLK) int4 packets per block
#define NB_PREPW 192

__device__ __forceinline__ float bflo(u32 u) {
    union { u32 i; float f; } v; v.i = u << 16; return v.f;
}
__device__ __forceinline__ float bfhi(u32 u) {
    union { u32 i; float f; } v; v.i = u & 0xFFFF0000u; return v.f;
}
__device__ __forceinline__ u16 f2bf(float f) {
    union { float f; u32 i; } v; v.f = f;
    u32 r = (v.i + 0x7FFFu + ((v.i >> 16) & 1u)) >> 16;
    return (u16)r;
}
__device__ __forceinline__ float fast_tanh(float x) {
    float e = __expf(2.0f * x);
    return 1.0f - 2.0f * __builtin_amdgcn_rcpf(e + 1.0f);
}

// ---------------- phase A1: per-block bucket histograms (LDS atomics only) + weight prep ----------------
// frag layout [m][ot][ks][lane][j]: ot=o>>4, ks=k>>5, quad=(k>>3)&3, j=k&7, lane=(quad<<4)|(o&15)

__global__ __launch_bounds__(256) void kA_count(const int* __restrict__ src, const int* __restrict__ dst,
                                                int* __restrict__ countsD, int* __restrict__ countsS,
                                                const float* __restrict__ w1, const float* __restrict__ w2,
                                                const float* __restrict__ v, u16* __restrict__ wvfrag) {
    __shared__ int cd[NBUK], cs[NBUK];
    if (blockIdx.x >= NBLK) {   // weight-frag prep blocks
        int idx = (blockIdx.x - NBLK) * 256 + threadIdx.x;   // 3*16384
        if (idx < 3 * 16384) {
            int m = idx >> 14, r = idx & 16383;
            int k = r >> 7, o = r & 127;
            float val = (m == 0) ? w1[k * 128 + o] : (m == 1) ? w2[k * 128 + o] : v[k * 128 + o];
            int ot = o >> 4, ks = k >> 5, quad = (k >> 3) & 3, j = k & 7;
            int lane = (quad << 4) | (o & 15);
            wvfrag[(((m * 8 + ot) * 4 + ks) * 64 + lane) * 8 + j] = f2bf(val);
        }
        return;
    }
    for (int i = threadIdx.x; i < NBUK; i += 256) { cd[i] = 0; cs[i] = 0; }
    __syncthreads();
    int i0 = blockIdx.x * CE;
    int i1 = i0 + CE; if (i1 > NE4) i1 = NE4;
    for (int i = i0 + threadIdx.x; i < i1; i += 256) {
        int4 d4 = ((const int4*)dst)[i];
        int4 s4 = ((const int4*)src)[i];
        atomicAdd(&cd[d4.x >> BSH], 1); atomicAdd(&cd[d4.y >> BSH], 1);
        atomicAdd(&cd[d4.z >> BSH], 1); atomicAdd(&cd[d4.w >> BSH], 1);
        atomicAdd(&cs[s4.x >> BSH], 1); atomicAdd(&cs[s4.y >> BSH], 1);
        atomicAdd(&cs[s4.z >> BSH], 1); atomicAdd(&cs[s4.w >> BSH], 1);
    }
    __syncthreads();
    for (int i = threadIdx.x; i < NBUK; i += 256) {
        countsD[i * NBLK + blockIdx.x] = cd[i];
        countsS[i * NBLK + blockIdx.x] = cs[i];
    }
}

// ---------------- phase A2: per-bucket exclusive scan over blocks (in-place) + bucket totals ----------------

__global__ __launch_bounds__(256) void kA_scan(int* __restrict__ countsD, int* __restrict__ countsS,
                                               int* __restrict__ totD, int* __restrict__ totS) {
    __shared__ int sc[256];
    int b = blockIdx.x;
    int* cnt = (b < NBUK) ? (countsD + b * NBLK) : (countsS + (b - NBUK) * NBLK);
    int t = threadIdx.x;
    int v0 = cnt[2 * t], v1 = cnt[2 * t + 1];
    int s = v0 + v1;
    sc[t] = s; __syncthreads();
    for (int off = 1; off < 256; off <<= 1) {
        int x = (t >= off) ? sc[t - off] : 0;
        __syncthreads();
        sc[t] += x;
        __syncthreads();
    }
    int excl = sc[t] - s;   // exclusive
    cnt[2 * t] = excl; cnt[2 * t + 1] = excl + v0;
    if (t == 255) { if (b < NBUK) totD[b] = sc[255]; else totS[b - NBUK] = sc[255]; }
}

// ---------------- phase A3: bucket-partition edges (LDS cursors; bases computed inline) ----------------

__global__ __launch_bounds__(256) void kA_scatter(const int* __restrict__ src, const int* __restrict__ dst,
                                                  const int* __restrict__ attr,
                                                  const int* __restrict__ countsD, const int* __restrict__ countsS,
                                                  const int* __restrict__ totD, const int* __restrict__ totS,
                                                  uint2* __restrict__ dbuf, int* __restrict__ sbuf) {
    __shared__ int curD[NBUK], curS[NBUK];
    __shared__ int sd[256], ss[256];
    int t = threadIdx.x;
    int vd = (t < NBUK) ? totD[t] : 0;
    int vs = (t < NBUK) ? totS[t] : 0;
    sd[t] = vd; ss[t] = vs; __syncthreads();
    for (int off = 1; off < 256; off <<= 1) {
        int xd = (t >= off) ? sd[t - off] : 0;
        int xs = (t >= off) ? ss[t - off] : 0;
        __syncthreads();
        sd[t] += xd; ss[t] += xs;
        __syncthreads();
    }
    if (t < NBUK) {
        curD[t] = (sd[t] - vd) + countsD[t * NBLK + blockIdx.x];
        curS[t] = (ss[t] - vs) + countsS[t * NBLK + blockIdx.x];
    }
    __syncthreads();
    int i0 = blockIdx.x * CE;
    int i1 = i0 + CE; if (i1 > NE4) i1 = NE4;
    for (int i = i0 + t; i < i1; i += 256) {
        int4 s4 = ((const int4*)src)[i];
        int4 d4 = ((const int4*)dst)[i];
        int4 a4 = ((const int4*)attr)[i];
        int p, d, s, a;
        d = d4.x; s = s4.x; a = a4.x;
        p = atomicAdd(&curD[d >> BSH], 1); dbuf[p] = make_uint2((u32)d, (u32)((s << 5) | a));
        p = atomicAdd(&curS[s >> BSH], 1); sbuf[p] = s;
        d = d4.y; s = s4.y; a = a4.y;
        p = atomicAdd(&curD[d >> BSH], 1); dbuf[p] = make_uint2((u32)d, (u32)((s << 5) | a));
        p = atomicAdd(&curS[s >> BSH], 1); sbuf[p] = s;
        d = d4.z; s = s4.z; a = a4.z;
        p = atomicAdd(&curD[d >> BSH], 1); dbuf[p] = make_uint2((u32)d, (u32)((s << 5) | a));
        p = atomicAdd(&curS[s >> BSH], 1); sbuf[p] = s;
        d = d4.w; s = s4.w; a = a4.w;
        p = atomicAdd(&curD[d >> BSH], 1); dbuf[p] = make_uint2((u32)d, (u32)((s << 5) | a));
        p = atomicAdd(&curS[s >> BSH], 1); sbuf[p] = s;
    }
}

// ---------------- phase B: per-bucket node counts + rank + CSR emit (all LDS) ----------------
// blocks [0,NBUK): dst path (in_deg/in_scale/csr_start/csr_edge); [NBUK,2*NBUK): src path (out_scale)

__global__ __launch_bounds__(256) void k_build(const uint2* __restrict__ dbuf, const int* __restrict__ sbuf,
                                               const int* __restrict__ totD, const int* __restrict__ totS,
                                               int* __restrict__ csr_start, int* __restrict__ in_deg,
                                               float* __restrict__ in_scale, float* __restrict__ out_scale,
                                               int* __restrict__ csr_edge) {
    __shared__ int cnt[512];
    __shared__ int aux[512];
    __shared__ int sc[256];
    __shared__ int sbase;
    int t = threadIdx.x;
    int isS = blockIdx.x >= NBUK;
    int b = isS ? (blockIdx.x - NBUK) : blockIdx.x;
    const int* tot = isS ? totS : totD;
    if (t < 64) {   // exclusive prefix of tot[0..b)
        int s = 0;
        for (int i = t; i < b; i += 64) s += tot[i];
#pragma unroll
        for (int o = 32; o > 0; o >>= 1) s += __shfl_down(s, o);
        if (t == 0) sbase = s;
    }
    for (int i = t; i < 512; i += 256) cnt[i] = 0;
    __syncthreads();
    int st = sbase, n = tot[b];
    int nb0 = b << BSH;
    if (isS) {
        for (int i = st + t; i < st + n; i += 256) atomicAdd(&cnt[sbuf[i] - nb0], 1);
        __syncthreads();
        for (int s2 = t; s2 < 512; s2 += 256) {
            int node = nb0 + s2;
            if (node < N_NODES) { int c = cnt[s2]; if (c < 1) c = 1; out_scale[node] = rsqrtf((float)c); }
        }
        return;
    }
    for (int i = st + t; i < st + n; i += 256) { uint2 r = dbuf[i]; atomicAdd(&cnt[(int)r.x - nb0], 1); }
    __syncthreads();
    int c0 = cnt[2 * t], c1 = cnt[2 * t + 1];
    int s = c0 + c1; sc[t] = s; __syncthreads();
    for (int off = 1; off < 256; off <<= 1) {
        int x = (t >= off) ? sc[t - off] : 0;
        __syncthreads();
        sc[t] += x;
        __syncthreads();
    }
    int excl = sc[t] - s;
    aux[2 * t] = excl; aux[2 * t + 1] = excl + c0;
    int na = nb0 + 2 * t, nbv = nb0 + 2 * t + 1;
    if (na < N_NODES) {
        in_deg[na] = c0; int cc = c0 < 1 ? 1 : c0;
        in_scale[na] = rsqrtf((float)cc); csr_start[na] = st + excl;
    }
    if (nbv < N_NODES) {
        in_deg[nbv] = c1; int cc = c1 < 1 ? 1 : c1;
        in_scale[nbv] = rsqrtf((float)cc); csr_start[nbv] = st + excl + c0;
    }
    __syncthreads();
    for (int i = st + t; i < st + n; i += 256) {
        uint2 r = dbuf[i];
        int pos = atomicAdd(&aux[(int)r.x - nb0], 1);
        csr_edge[st + pos] = (int)r.y;
    }
}

// ---------------- fused node GEMMs, NO LDS: B-frags streamed from global (L1/L2-resident 64 KB) ----------------
// hrow layout (256 u16 per node): u16 idx 2o = h_sum(o), 2o+1 = h_prod(o)  -> one u32 per (node,o)

__global__ __launch_bounds__(256) void k_gemm(const float* __restrict__ feat,
                                              const float* __restrict__ out_scale,
                                              const u16* __restrict__ wvfrag,
                                              const float* __restrict__ w2,
                                              u16* __restrict__ hrow) {
    int wave = threadIdx.x >> 6, lane = threadIdx.x & 63;
    int quad = lane >> 4, l15 = lane & 15;
    const float* bias = w2 + 128 * 128;
    float bias_v[8];
#pragma unroll
    for (int ot = 0; ot < 8; ot++) bias_v[ot] = bias[ot * 16 + l15];
    const short8* wv = (const short8*)wvfrag;   // frag idx = ((m*8+ot)*4+ks)*64 + lane
    int nb = blockIdx.x * 64 + wave * 16;
    int anode = nb + l15; if (anode >= N_NODES) anode = N_NODES - 1;
    float s = out_scale[anode];
    short8 a[4];
#pragma unroll
    for (int ks = 0; ks < 4; ks++) {
        float4 f0 = *(const float4*)(feat + anode * 128 + ks * 32 + quad * 8);
        float4 f1 = *(const float4*)(feat + anode * 128 + ks * 32 + quad * 8 + 4);
        short8 av;
        av[0] = (short)f2bf(f0.x * s); av[1] = (short)f2bf(f0.y * s);
        av[2] = (short)f2bf(f0.z * s); av[3] = (short)f2bf(f0.w * s);
        av[4] = (short)f2bf(f1.x * s); av[5] = (short)f2bf(f1.y * s);
        av[6] = (short)f2bf(f1.z * s); av[7] = (short)f2bf(f1.w * s);
        a[ks] = av;
    }
#pragma unroll
    for (int ot = 0; ot < 8; ot++) {
        floatx4 accS = (floatx4){0.f, 0.f, 0.f, 0.f};
        floatx4 accP = (floatx4){0.f, 0.f, 0.f, 0.f};
#pragma unroll
        for (int ks = 0; ks < 4; ks++) {
            short8 b0 = wv[(ot * 4 + ks) * 64 + lane];
            short8 b1 = wv[((8 + ot) * 4 + ks) * 64 + lane];
            accS = __builtin_amdgcn_mfma_f32_16x16x32_bf16(a[ks], b0, accS, 0, 0, 0);
            accP = __builtin_amdgcn_mfma_f32_16x16x32_bf16(a[ks], b1, accP, 0, 0, 0);
        }
        int o = ot * 16 + l15;
#pragma unroll
        for (int r = 0; r < 4; r++) {
            int node = nb + quad * 4 + r;
            if (node < N_NODES) {
                u32 pv = (u32)f2bf(accS[r]) | ((u32)f2bf(fast_tanh(accP[r] + bias_v[ot])) << 16);
                *(u32*)(hrow + node * 256 + o * 2) = pv;  // coalesced: 16 lanes -> 64 B line
            }
        }
    }
}

// ---------------- edge stage: FROZEN R4 structure (guarded dual-stream depth-2, static stride) ----------------
// Measured 78.4 us twice; edge-balancing (R6), branch-free (R1), bond-LDS (R5) all regressed it.
// hrow uint2 per lane: .x = {sum(2l) | prod(2l)<<16}, .y = {sum(2l+1) | prod(2l+1)<<16}

__global__ __launch_bounds__(256, 8) void k_edge(const int* __restrict__ csr_start, const int* __restrict__ in_deg,
                                                 const int* __restrict__ csr_edge,
                                                 const u16* __restrict__ hrow,
                                                 const float* __restrict__ bond_emb,
                                                 float* __restrict__ out_hs, u16* __restrict__ hp) {
    int wid = (blockIdx.x * 256 + threadIdx.x) >> 6;
    int lane = threadIdx.x & 63;
    int nwaves = (gridDim.x * 256) >> 6;
    const int NPAIR = N_NODES / 2;
    uint2 hC0 = {0, 0}, hC1 = {0, 0};
    float2 eC0 = {0.f, 0.f}, eC1 = {0.f, 0.f};
    for (int pr = wid; pr < NPAIR; pr += nwaves) {
        int n0 = pr * 2, n1 = n0 + 1;
        int st0 = csr_start[n0];
        int2 dd = *(const int2*)(in_deg + n0);     // n0 even -> 8B aligned
        int d0 = dd.x, d1 = dd.y;
        int st1 = st0 + d0;                         // CSR prefix property
        float as0 = 0.f, as1 = 0.f, ap0 = 1.f, ap1 = 1.f;
        float bs0 = 0.f, bs1 = 0.f, bp0 = 1.f, bp1 = 1.f;
        int b0 = 0, b1 = 0;
        while (b0 < d0 || b1 < d1) {
            int c0 = d0 - b0; c0 = c0 < 0 ? 0 : (c0 > 64 ? 64 : c0);
            int c1 = d1 - b1; c1 = c1 < 0 ? 0 : (c1 > 64 ? 64 : c1);
            int pkv0 = 0, pkv1 = 0;
            if (c0 > 0) { int li = lane < c0 ? lane : c0 - 1; pkv0 = csr_edge[st0 + b0 + li]; }
            if (c1 > 0) { int li = lane < c1 ? lane : c1 - 1; pkv1 = csr_edge[st1 + b1 + li]; }
            uint2 hA0 = hC0, hB0 = hC0, hA1 = hC1, hB1 = hC1;
            float2 eA0 = eC0, eB0 = eC0, eA1 = eC1, eB1 = eC1;
            if (c0 > 0) {
                int pk = __builtin_amdgcn_readlane(pkv0, 0);
                hA0 = *(const uint2*)(hrow + (pk >> 5) * 256 + 4 * lane);
                eA0 = *(const float2*)(bond_emb + (pk & 31) * 128 + 2 * lane);
                if (c0 > 1) {
                    pk = __builtin_amdgcn_readlane(pkv0, 1);
                    hB0 = *(const uint2*)(hrow + (pk >> 5) * 256 + 4 * lane);
                    eB0 = *(const float2*)(bond_emb + (pk & 31) * 128 + 2 * lane);
                }
            }
            if (c1 > 0) {
                int pk = __builtin_amdgcn_readlane(pkv1, 0);
                hA1 = *(const uint2*)(hrow + (pk >> 5) * 256 + 4 * lane);
                eA1 = *(const float2*)(bond_emb + (pk & 31) * 128 + 2 * lane);
                if (c1 > 1) {
                    pk = __builtin_amdgcn_readlane(pkv1, 1);
                    hB1 = *(const uint2*)(hrow + (pk >> 5) * 256 + 4 * lane);
                    eB1 = *(const float2*)(bond_emb + (pk & 31) * 128 + 2 * lane);
                }
            }
            int cm = c0 > c1 ? c0 : c1;
            for (int j = 0; j < cm; j++) {
                int jn = j + 2;
                if (jn < c0) {
                    int pk = __builtin_amdgcn_readlane(pkv0, jn);
                    hC0 = *(const uint2*)(hrow + (pk >> 5) * 256 + 4 * lane);
                    eC0 = *(const float2*)(bond_emb + (pk & 31) * 128 + 2 * lane);
                }
                if (jn < c1) {
                    int pk = __builtin_amdgcn_readlane(pkv1, jn);
                    hC1 = *(const uint2*)(hrow + (pk >> 5) * 256 + 4 * lane);
                    eC1 = *(const float2*)(bond_emb + (pk & 31) * 128 + 2 * lane);
                }
                if (j < c0) {
                    as0 += bflo(hA0.x) * eA0.x;
                    ap0 *= bfhi(hA0.x) * eA0.x;
                    as1 += bflo(hA0.y) * eA0.y;
                    ap1 *= bfhi(hA0.y) * eA0.y;
                    hA0 = hB0; eA0 = eB0; hB0 = hC0; eB0 = eC0;
                }
                if (j < c1) {
                    bs0 += bflo(hA1.x) * eA1.x;
                    bp0 *= bfhi(hA1.x) * eA1.x;
                    bs1 += bflo(hA1.y) * eA1.y;
                    bp1 *= bfhi(hA1.y) * eA1.y;
                    hA1 = hB1; eA1 = eB1; hB1 = hC1; eB1 = eC1;
                }
            }
            b0 += 64; b1 += 64;
        }
        float2 sv0; sv0.x = as0; sv0.y = as1;
        float2 sv1; sv1.x = bs0; sv1.y = bs1;
        *(float2*)(out_hs + n0 * 128 + 2 * lane) = sv0;
        *(float2*)(out_hs + n1 * 128 + 2 * lane) = sv1;
        *(u32*)(hp + n0 * 128 + 2 * lane) = ((u32)f2bf(ap1) << 16) | (u32)f2bf(ap0);
        *(u32*)(hp + n1 * 128 + 2 * lane) = ((u32)f2bf(bp1) << 16) | (u32)f2bf(bp0);
    }
}

// ---------------- final: out = (hs + hp@v) * in_scale, NO LDS (vfrag from global, L1-resident) ----------------

__global__ __launch_bounds__(256) void k_final(const u16* __restrict__ hp,
                                               const u16* __restrict__ vfrag,
                                               const float* __restrict__ in_scale,
                                               float* __restrict__ out) {
    int wave = threadIdx.x >> 6, lane = threadIdx.x & 63;
    int quad = lane >> 4, l15 = lane & 15;
    const short8* wv = (const short8*)vfrag;   // frag idx = (ot*4+ks)*64 + lane
    int nb = blockIdx.x * 64 + wave * 16;
    int anode = nb + l15; if (anode >= N_NODES) anode = N_NODES - 1;
    short8 a[4];
#pragma unroll
    for (int ks = 0; ks < 4; ks++)
        a[ks] = *(const short8*)(hp + anode * 128 + ks * 32 + quad * 8);
#pragma unroll
    for (int ot = 0; ot < 8; ot++) {
        floatx4 acc = (floatx4){0.f, 0.f, 0.f, 0.f};
#pragma unroll
        for (int ks = 0; ks < 4; ks++) {
            short8 b = wv[(ot * 4 + ks) * 64 + lane];
            acc = __builtin_amdgcn_mfma_f32_16x16x32_bf16(a[ks], b, acc, 0, 0, 0);
        }
        int o = ot * 16 + l15;
#pragma unroll
        for (int r = 0; r < 4; r++) {
            int node = nb + quad * 4 + r;
            if (node < N_NODES) {
                float scl = in_scale[node];
                float hsv = out[node * 128 + o];          // hs, written by k_edge
                out[node * 128 + o] = (acc[r] + hsv) * scl;
            }
        }
    }
}

extern "C" void kernel_launch(void* const* d_in, const int* in_sizes, int n_in,
                              void* d_out, int out_size, void* d_ws, size_t ws_size,
                              hipStream_t stream) {
    const float* feat = (const float*)d_in[0];
    const int* src = (const int*)d_in[1];
    const int* dst = (const int*)d_in[2];
    const int* attr = (const int*)d_in[3];
    const float* w1 = (const float*)d_in[4];
    const float* w2 = (const float*)d_in[5];
    const float* v = (const float*)d_in[6];
    const float* bond = (const float*)d_in[7];
    float* out = (float*)d_out;

    char* ws = (char*)d_ws;
    size_t off = 0;
    auto alloc = [&](size_t bytes) -> char* {
        char* p = ws + off; off += (bytes + 255) & ~(size_t)255; return p;
    };
    int* countsD   = (int*)alloc((size_t)NBUK * NBLK * 4);
    int* countsS   = (int*)alloc((size_t)NBUK * NBLK * 4);
    int* totD      = (int*)alloc((size_t)NBUK * 4);
    int* totS      = (int*)alloc((size_t)NBUK * 4);
    uint2* dbuf    = (uint2*)alloc((size_t)N_EDGES * 8);
    int* sbuf      = (int*)alloc((size_t)N_EDGES * 4);
    int* csr_start = (int*)alloc((size_t)N_NODES * 4);
    int* in_deg    = (int*)alloc((size_t)N_NODES * 4);
    float* out_scale = (float*)alloc((size_t)N_NODES * 4);
    float* in_scale  = (float*)alloc((size_t)N_NODES * 4);
    int* csr_edge  = (int*)alloc((size_t)N_EDGES * 4);
    u16* wvfrag = (u16*)alloc((size_t)3 * 16384 * 2);         // w1|w2|v bf16 frags
    u16* hrow   = (u16*)alloc((size_t)N_NODES * 256 * 2);     // [sum|prod] per channel
    u16* hp     = (u16*)alloc((size_t)N_NODES * 128 * 2);

    (void)in_sizes; (void)n_in; (void)out_size; (void)ws_size;

    kA_count<<<NBLK + NB_PREPW, 256, 0, stream>>>(src, dst, countsD, countsS, w1, w2, v, wvfrag);
    kA_scan<<<2 * NBUK, 256, 0, stream>>>(countsD, countsS, totD, totS);
    kA_scatter<<<NBLK, 256, 0, stream>>>(src, dst, attr, countsD, countsS, totD, totS, dbuf, sbuf);
    k_build<<<2 * NBUK, 256, 0, stream>>>(dbuf, sbuf, totD, totS,
                                          csr_start, in_deg, in_scale, out_scale, csr_edge);
    k_gemm<<<(N_NODES + 63) / 64, 256, 0, stream>>>(feat, out_scale, wvfrag, w2, hrow);
    k_edge<<<2048, 256, 0, stream>>>(csr_start, in_deg, csr_edge, hrow, bond, out, hp);
    k_final<<<(N_NODES + 63) / 64, 256, 0, stream>>>(hp, wvfrag + 2 * 16384, in_scale, out);
}

// Round 8
// 265.083 us; speedup vs baseline: 1.1412x; 1.0139x over previous
//
#include <hip/hip_runtime.h>

#define N_NODES 100000
#define N_EDGES 800000

typedef unsigned short u16;
typedef unsigned int u32;
typedef __attribute__((ext_vector_type(8))) short short8;
typedef __attribute__((ext_vector_type(4))) float floatx4;

#define NBUK 196            // ceil(100000 / 512)
#define BSH 9               // bucket = node >> 9  (512 nodes/bucket)
#define NBLK 256            // edge-partition blocks (contiguous ranges; 1 block/CU)
#define NE4 (N_EDGES / 4)   // 200000 int4 packets
#define CE 782              // ceil(NE4 / NBLK) int4 packets per block
#define NB_PREPW 192

__device__ __forceinline__ float bflo(u32 u) {
    union { u32 i; float f; } v; v.i = u << 16; return v.f;
}
__device__ __forceinline__ float bfhi(u32 u) {
    union { u32 i; float f; } v; v.i = u & 0xFFFF0000u; return v.f;
}
__device__ __forceinline__ u16 f2bf(float f) {
    union { float f; u32 i; } v; v.f = f;
    u32 r = (v.i + 0x7FFFu + ((v.i >> 16) & 1u)) >> 16;
    return (u16)r;
}
__device__ __forceinline__ float fast_tanh(float x) {
    float e = __expf(2.0f * x);
    return 1.0f - 2.0f * __builtin_amdgcn_rcpf(e + 1.0f);
}

// ---------------- phase A1: per-block bucket histograms (LDS atomics only) + weight prep ----------------
// frag layout [m][ot][ks][lane][j]: ot=o>>4, ks=k>>5, quad=(k>>3)&3, j=k&7, lane=(quad<<4)|(o&15)

__global__ __launch_bounds__(256) void kA_count(const int* __restrict__ src, const int* __restrict__ dst,
                                                int* __restrict__ countsD, int* __restrict__ countsS,
                                                const float* __restrict__ w1, const float* __restrict__ w2,
                                                const float* __restrict__ v, u16* __restrict__ wvfrag) {
    __shared__ int cd[NBUK], cs[NBUK];
    if (blockIdx.x >= NBLK) {   // weight-frag prep blocks
        int idx = (blockIdx.x - NBLK) * 256 + threadIdx.x;   // 3*16384
        if (idx < 3 * 16384) {
            int m = idx >> 14, r = idx & 16383;
            int k = r >> 7, o = r & 127;
            float val = (m == 0) ? w1[k * 128 + o] : (m == 1) ? w2[k * 128 + o] : v[k * 128 + o];
            int ot = o >> 4, ks = k >> 5, quad = (k >> 3) & 3, j = k & 7;
            int lane = (quad << 4) | (o & 15);
            wvfrag[(((m * 8 + ot) * 4 + ks) * 64 + lane) * 8 + j] = f2bf(val);
        }
        return;
    }
    for (int i = threadIdx.x; i < NBUK; i += 256) { cd[i] = 0; cs[i] = 0; }
    __syncthreads();
    int i0 = blockIdx.x * CE;
    int i1 = i0 + CE; if (i1 > NE4) i1 = NE4;
    for (int i = i0 + threadIdx.x; i < i1; i += 256) {
        int4 d4 = ((const int4*)dst)[i];
        int4 s4 = ((const int4*)src)[i];
        atomicAdd(&cd[d4.x >> BSH], 1); atomicAdd(&cd[d4.y >> BSH], 1);
        atomicAdd(&cd[d4.z >> BSH], 1); atomicAdd(&cd[d4.w >> BSH], 1);
        atomicAdd(&cs[s4.x >> BSH], 1); atomicAdd(&cs[s4.y >> BSH], 1);
        atomicAdd(&cs[s4.z >> BSH], 1); atomicAdd(&cs[s4.w >> BSH], 1);
    }
    __syncthreads();
    for (int i = threadIdx.x; i < NBUK; i += 256) {
        countsD[i * NBLK + blockIdx.x] = cd[i];
        countsS[i * NBLK + blockIdx.x] = cs[i];
    }
}

// ---------------- phase A2: per-bucket exclusive scan over blocks (in-place) + bucket totals ----------------

__global__ __launch_bounds__(256) void kA_scan(int* __restrict__ countsD, int* __restrict__ countsS,
                                               int* __restrict__ totD, int* __restrict__ totS) {
    __shared__ int sc[256];
    int b = blockIdx.x;
    int* cnt = (b < NBUK) ? (countsD + b * NBLK) : (countsS + (b - NBUK) * NBLK);
    int t = threadIdx.x;
    int v0 = cnt[t];           // NBLK == 256: one entry per thread
    sc[t] = v0; __syncthreads();
    for (int off = 1; off < 256; off <<= 1) {
        int x = (t >= off) ? sc[t - off] : 0;
        __syncthreads();
        sc[t] += x;
        __syncthreads();
    }
    cnt[t] = sc[t] - v0;       // exclusive
    if (t == 255) { if (b < NBUK) totD[b] = sc[255]; else totS[b - NBUK] = sc[255]; }
}

// ---------------- phase A3: bucket-partition edges (LDS cursors; bases computed inline) ----------------
// dbuf record (4B): (local_dst<<22) | (src<<5) | attr   [9+17+5 = 31 bits]
// sbuf record (2B): local_src

__global__ __launch_bounds__(256) void kA_scatter(const int* __restrict__ src, const int* __restrict__ dst,
                                                  const int* __restrict__ attr,
                                                  const int* __restrict__ countsD, const int* __restrict__ countsS,
                                                  const int* __restrict__ totD, const int* __restrict__ totS,
                                                  u32* __restrict__ dbuf, u16* __restrict__ sbuf) {
    __shared__ int curD[NBUK], curS[NBUK];
    __shared__ int sd[256], ss[256];
    int t = threadIdx.x;
    int vd = (t < NBUK) ? totD[t] : 0;
    int vs = (t < NBUK) ? totS[t] : 0;
    sd[t] = vd; ss[t] = vs; __syncthreads();
    for (int off = 1; off < 256; off <<= 1) {
        int xd = (t >= off) ? sd[t - off] : 0;
        int xs = (t >= off) ? ss[t - off] : 0;
        __syncthreads();
        sd[t] += xd; ss[t] += xs;
        __syncthreads();
    }
    if (t < NBUK) {
        curD[t] = (sd[t] - vd) + countsD[t * NBLK + blockIdx.x];
        curS[t] = (ss[t] - vs) + countsS[t * NBLK + blockIdx.x];
    }
    __syncthreads();
    int i0 = blockIdx.x * CE;
    int i1 = i0 + CE; if (i1 > NE4) i1 = NE4;
    for (int i = i0 + t; i < i1; i += 256) {
        int4 s4 = ((const int4*)src)[i];
        int4 d4 = ((const int4*)dst)[i];
        int4 a4 = ((const int4*)attr)[i];
        int p, d, s, a;
        d = d4.x; s = s4.x; a = a4.x;
        p = atomicAdd(&curD[d >> BSH], 1);
        dbuf[p] = ((u32)(d & 511) << 22) | ((u32)s << 5) | (u32)a;
        p = atomicAdd(&curS[s >> BSH], 1); sbuf[p] = (u16)(s & 511);
        d = d4.y; s = s4.y; a = a4.y;
        p = atomicAdd(&curD[d >> BSH], 1);
        dbuf[p] = ((u32)(d & 511) << 22) | ((u32)s << 5) | (u32)a;
        p = atomicAdd(&curS[s >> BSH], 1); sbuf[p] = (u16)(s & 511);
        d = d4.z; s = s4.z; a = a4.z;
        p = atomicAdd(&curD[d >> BSH], 1);
        dbuf[p] = ((u32)(d & 511) << 22) | ((u32)s << 5) | (u32)a;
        p = atomicAdd(&curS[s >> BSH], 1); sbuf[p] = (u16)(s & 511);
        d = d4.w; s = s4.w; a = a4.w;
        p = atomicAdd(&curD[d >> BSH], 1);
        dbuf[p] = ((u32)(d & 511) << 22) | ((u32)s << 5) | (u32)a;
        p = atomicAdd(&curS[s >> BSH], 1); sbuf[p] = (u16)(s & 511);
    }
}

// ---------------- phase B: per-bucket node counts + rank + CSR emit (all LDS) ----------------
// blocks [0,NBUK): dst path (in_deg/in_scale/csr_start/csr_edge); [NBUK,2*NBUK): src path (out_scale)

__global__ __launch_bounds__(256) void k_build(const u32* __restrict__ dbuf, const u16* __restrict__ sbuf,
                                               const int* __restrict__ totD, const int* __restrict__ totS,
                                               int* __restrict__ csr_start, int* __restrict__ in_deg,
                                               float* __restrict__ in_scale, float* __restrict__ out_scale,
                                               int* __restrict__ csr_edge) {
    __shared__ int cnt[512];
    __shared__ int aux[512];
    __shared__ int sc[256];
    __shared__ int sbase;
    int t = threadIdx.x;
    int isS = blockIdx.x >= NBUK;
    int b = isS ? (blockIdx.x - NBUK) : blockIdx.x;
    const int* tot = isS ? totS : totD;
    if (t < 64) {   // exclusive prefix of tot[0..b)
        int s = 0;
        for (int i = t; i < b; i += 64) s += tot[i];
#pragma unroll
        for (int o = 32; o > 0; o >>= 1) s += __shfl_down(s, o);
        if (t == 0) sbase = s;
    }
    for (int i = t; i < 512; i += 256) cnt[i] = 0;
    __syncthreads();
    int st = sbase, n = tot[b];
    int nb0 = b << BSH;
    if (isS) {
        for (int i = st + t; i < st + n; i += 256) atomicAdd(&cnt[sbuf[i]], 1);
        __syncthreads();
        for (int s2 = t; s2 < 512; s2 += 256) {
            int node = nb0 + s2;
            if (node < N_NODES) { int c = cnt[s2]; if (c < 1) c = 1; out_scale[node] = rsqrtf((float)c); }
        }
        return;
    }
    for (int i = st + t; i < st + n; i += 256) { u32 r = dbuf[i]; atomicAdd(&cnt[r >> 22], 1); }
    __syncthreads();
    int c0 = cnt[2 * t], c1 = cnt[2 * t + 1];
    int s = c0 + c1; sc[t] = s; __syncthreads();
    for (int off = 1; off < 256; off <<= 1) {
        int x = (t >= off) ? sc[t - off] : 0;
        __syncthreads();
        sc[t] += x;
        __syncthreads();
    }
    int excl = sc[t] - s;
    aux[2 * t] = excl; aux[2 * t + 1] = excl + c0;
    int na = nb0 + 2 * t, nbv = nb0 + 2 * t + 1;
    if (na < N_NODES) {
        in_deg[na] = c0; int cc = c0 < 1 ? 1 : c0;
        in_scale[na] = rsqrtf((float)cc); csr_start[na] = st + excl;
    }
    if (nbv < N_NODES) {
        in_deg[nbv] = c1; int cc = c1 < 1 ? 1 : c1;
        in_scale[nbv] = rsqrtf((float)cc); csr_start[nbv] = st + excl + c0;
    }
    __syncthreads();
    for (int i = st + t; i < st + n; i += 256) {
        u32 r = dbuf[i];
        int pos = atomicAdd(&aux[r >> 22], 1);
        csr_edge[st + pos] = (int)(r & 0x3FFFFFu);   // (src<<5)|attr
    }
}

// ---------------- fused node GEMMs, NO LDS: B-frags streamed from global (L1/L2-resident 64 KB) ----------------
// hrow layout (256 u16 per node): u16 idx 2o = h_sum(o), 2o+1 = h_prod(o)  -> one u32 per (node,o)

__global__ __launch_bounds__(256) void k_gemm(const float* __restrict__ feat,
                                              const float* __restrict__ out_scale,
                                              const u16* __restrict__ wvfrag,
                                              const float* __restrict__ w2,
                                              u16* __restrict__ hrow) {
    int wave = threadIdx.x >> 6, lane = threadIdx.x & 63;
    int quad = lane >> 4, l15 = lane & 15;
    const float* bias = w2 + 128 * 128;
    float bias_v[8];
#pragma unroll
    for (int ot = 0; ot < 8; ot++) bias_v[ot] = bias[ot * 16 + l15];
    const short8* wv = (const short8*)wvfrag;   // frag idx = ((m*8+ot)*4+ks)*64 + lane
    int nb = blockIdx.x * 64 + wave * 16;
    int anode = nb + l15; if (anode >= N_NODES) anode = N_NODES - 1;
    float s = out_scale[anode];
    short8 a[4];
#pragma unroll
    for (int ks = 0; ks < 4; ks++) {
        float4 f0 = *(const float4*)(feat + anode * 128 + ks * 32 + quad * 8);
        float4 f1 = *(const float4*)(feat + anode * 128 + ks * 32 + quad * 8 + 4);
        short8 av;
        av[0] = (short)f2bf(f0.x * s); av[1] = (short)f2bf(f0.y * s);
        av[2] = (short)f2bf(f0.z * s); av[3] = (short)f2bf(f0.w * s);
        av[4] = (short)f2bf(f1.x * s); av[5] = (short)f2bf(f1.y * s);
        av[6] = (short)f2bf(f1.z * s); av[7] = (short)f2bf(f1.w * s);
        a[ks] = av;
    }
#pragma unroll
    for (int ot = 0; ot < 8; ot++) {
        floatx4 accS = (floatx4){0.f, 0.f, 0.f, 0.f};
        floatx4 accP = (floatx4){0.f, 0.f, 0.f, 0.f};
#pragma unroll
        for (int ks = 0; ks < 4; ks++) {
            short8 b0 = wv[(ot * 4 + ks) * 64 + lane];
            short8 b1 = wv[((8 + ot) * 4 + ks) * 64 + lane];
            accS = __builtin_amdgcn_mfma_f32_16x16x32_bf16(a[ks], b0, accS, 0, 0, 0);
            accP = __builtin_amdgcn_mfma_f32_16x16x32_bf16(a[ks], b1, accP, 0, 0, 0);
        }
        int o = ot * 16 + l15;
#pragma unroll
        for (int r = 0; r < 4; r++) {
            int node = nb + quad * 4 + r;
            if (node < N_NODES) {
                u32 pv = (u32)f2bf(accS[r]) | ((u32)f2bf(fast_tanh(accP[r] + bias_v[ot])) << 16);
                *(u32*)(hrow + node * 256 + o * 2) = pv;  // coalesced: 16 lanes -> 64 B line
            }
        }
    }
}

// ---------------- edge stage: FROZEN R4 structure (guarded dual-stream depth-2, static stride) ----------------
// Measured 78.4-79.5 us four times; edge-balancing (R6), branch-free (R1), bond-LDS (R5),
// dynamic queue (R2) all regressed it. Do not touch.
// hrow uint2 per lane: .x = {sum(2l) | prod(2l)<<16}, .y = {sum(2l+1) | prod(2l+1)<<16}

__global__ __launch_bounds__(256, 8) void k_edge(const int* __restrict__ csr_start, const int* __restrict__ in_deg,
                                                 const int* __restrict__ csr_edge,
                                                 const u16* __restrict__ hrow,
                                                 const float* __restrict__ bond_emb,
                                                 float* __restrict__ out_hs, u16* __restrict__ hp) {
    int wid = (blockIdx.x * 256 + threadIdx.x) >> 6;
    int lane = threadIdx.x & 63;
    int nwaves = (gridDim.x * 256) >> 6;
    const int NPAIR = N_NODES / 2;
    uint2 hC0 = {0, 0}, hC1 = {0, 0};
    float2 eC0 = {0.f, 0.f}, eC1 = {0.f, 0.f};
    for (int pr = wid; pr < NPAIR; pr += nwaves) {
        int n0 = pr * 2, n1 = n0 + 1;
        int st0 = csr_start[n0];
        int2 dd = *(const int2*)(in_deg + n0);     // n0 even -> 8B aligned
        int d0 = dd.x, d1 = dd.y;
        int st1 = st0 + d0;                         // CSR prefix property
        float as0 = 0.f, as1 = 0.f, ap0 = 1.f, ap1 = 1.f;
        float bs0 = 0.f, bs1 = 0.f, bp0 = 1.f, bp1 = 1.f;
        int b0 = 0, b1 = 0;
        while (b0 < d0 || b1 < d1) {
            int c0 = d0 - b0; c0 = c0 < 0 ? 0 : (c0 > 64 ? 64 : c0);
            int c1 = d1 - b1; c1 = c1 < 0 ? 0 : (c1 > 64 ? 64 : c1);
            int pkv0 = 0, pkv1 = 0;
            if (c0 > 0) { int li = lane < c0 ? lane : c0 - 1; pkv0 = csr_edge[st0 + b0 + li]; }
            if (c1 > 0) { int li = lane < c1 ? lane : c1 - 1; pkv1 = csr_edge[st1 + b1 + li]; }
            uint2 hA0 = hC0, hB0 = hC0, hA1 = hC1, hB1 = hC1;
            float2 eA0 = eC0, eB0 = eC0, eA1 = eC1, eB1 = eC1;
            if (c0 > 0) {
                int pk = __builtin_amdgcn_readlane(pkv0, 0);
                hA0 = *(const uint2*)(hrow + (pk >> 5) * 256 + 4 * lane);
                eA0 = *(const float2*)(bond_emb + (pk & 31) * 128 + 2 * lane);
                if (c0 > 1) {
                    pk = __builtin_amdgcn_readlane(pkv0, 1);
                    hB0 = *(const uint2*)(hrow + (pk >> 5) * 256 + 4 * lane);
                    eB0 = *(const float2*)(bond_emb + (pk & 31) * 128 + 2 * lane);
                }
            }
            if (c1 > 0) {
                int pk = __builtin_amdgcn_readlane(pkv1, 0);
                hA1 = *(const uint2*)(hrow + (pk >> 5) * 256 + 4 * lane);
                eA1 = *(const float2*)(bond_emb + (pk & 31) * 128 + 2 * lane);
                if (c1 > 1) {
                    pk = __builtin_amdgcn_readlane(pkv1, 1);
                    hB1 = *(const uint2*)(hrow + (pk >> 5) * 256 + 4 * lane);
                    eB1 = *(const float2*)(bond_emb + (pk & 31) * 128 + 2 * lane);
                }
            }
            int cm = c0 > c1 ? c0 : c1;
            for (int j = 0; j < cm; j++) {
                int jn = j + 2;
                if (jn < c0) {
                    int pk = __builtin_amdgcn_readlane(pkv0, jn);
                    hC0 = *(const uint2*)(hrow + (pk >> 5) * 256 + 4 * lane);
                    eC0 = *(const float2*)(bond_emb + (pk & 31) * 128 + 2 * lane);
                }
                if (jn < c1) {
                    int pk = __builtin_amdgcn_readlane(pkv1, jn);
                    hC1 = *(const uint2*)(hrow + (pk >> 5) * 256 + 4 * lane);
                    eC1 = *(const float2*)(bond_emb + (pk & 31) * 128 + 2 * lane);
                }
                if (j < c0) {
                    as0 += bflo(hA0.x) * eA0.x;
                    ap0 *= bfhi(hA0.x) * eA0.x;
                    as1 += bflo(hA0.y) * eA0.y;
                    ap1 *= bfhi(hA0.y) * eA0.y;
                    hA0 = hB0; eA0 = eB0; hB0 = hC0; eB0 = eC0;
                }
                if (j < c1) {
                    bs0 += bflo(hA1.x) * eA1.x;
                    bp0 *= bfhi(hA1.x) * eA1.x;
                    bs1 += bflo(hA1.y) * eA1.y;
                    bp1 *= bfhi(hA1.y) * eA1.y;
                    hA1 = hB1; eA1 = eB1; hB1 = hC1; eB1 = eC1;
                }
            }
            b0 += 64; b1 += 64;
        }
        float2 sv0; sv0.x = as0; sv0.y = as1;
        float2 sv1; sv1.x = bs0; sv1.y = bs1;
        *(float2*)(out_hs + n0 * 128 + 2 * lane) = sv0;
        *(float2*)(out_hs + n1 * 128 + 2 * lane) = sv1;
        *(u32*)(hp + n0 * 128 + 2 * lane) = ((u32)f2bf(ap1) << 16) | (u32)f2bf(ap0);
        *(u32*)(hp + n1 * 128 + 2 * lane) = ((u32)f2bf(bp1) << 16) | (u32)f2bf(bp0);
    }
}

// ---------------- final: out = (hs + hp@v) * in_scale, NO LDS (vfrag from global, L1-resident) ----------------

__global__ __launch_bounds__(256) void k_final(const u16* __restrict__ hp,
                                               const u16* __restrict__ vfrag,
                                               const float* __restrict__ in_scale,
                                               float* __restrict__ out) {
    int wave = threadIdx.x >> 6, lane = threadIdx.x & 63;
    int quad = lane >> 4, l15 = lane & 15;
    const short8* wv = (const short8*)vfrag;   // frag idx = (ot*4+ks)*64 + lane
    int nb = blockIdx.x * 64 + wave * 16;
    int anode = nb + l15; if (anode >= N_NODES) anode = N_NODES - 1;
    short8 a[4];
#pragma unroll
    for (int ks = 0; ks < 4; ks++)
        a[ks] = *(const short8*)(hp + anode * 128 + ks * 32 + quad * 8);
#pragma unroll
    for (int ot = 0; ot < 8; ot++) {
        floatx4 acc = (floatx4){0.f, 0.f, 0.f, 0.f};
#pragma unroll
        for (int ks = 0; ks < 4; ks++) {
            short8 b = wv[(ot * 4 + ks) * 64 + lane];
            acc = __builtin_amdgcn_mfma_f32_16x16x32_bf16(a[ks], b, acc, 0, 0, 0);
        }
        int o = ot * 16 + l15;
#pragma unroll
        for (int r = 0; r < 4; r++) {
            int node = nb + quad * 4 + r;
            if (node < N_NODES) {
                float scl = in_scale[node];
                float hsv = out[node * 128 + o];          // hs, written by k_edge
                out[node * 128 + o] = (acc[r] + hsv) * scl;
            }
        }
    }
}

extern "C" void kernel_launch(void* const* d_in, const int* in_sizes, int n_in,
                              void* d_out, int out_size, void* d_ws, size_t ws_size,
                              hipStream_t stream) {
    const float* feat = (const float*)d_in[0];
    const int* src = (const int*)d_in[1];
    const int* dst = (const int*)d_in[2];
    const int* attr = (const int*)d_in[3];
    const float* w1 = (const float*)d_in[4];
    const float* w2 = (const float*)d_in[5];
    const float* v = (const float*)d_in[6];
    const float* bond = (const float*)d_in[7];
    float* out = (float*)d_out;

    char* ws = (char*)d_ws;
    size_t off = 0;
    auto alloc = [&](size_t bytes) -> char* {
        char* p = ws + off; off += (bytes + 255) & ~(size_t)255; return p;
    };
    int* countsD   = (int*)alloc((size_t)NBUK * NBLK * 4);
    int* countsS   = (int*)alloc((size_t)NBUK * NBLK * 4);
    int* totD      = (int*)alloc((size_t)NBUK * 4);
    int* totS      = (int*)alloc((size_t)NBUK * 4);
    u32* dbuf      = (u32*)alloc((size_t)N_EDGES * 4);
    u16* sbuf      = (u16*)alloc((size_t)N_EDGES * 2);
    int* csr_start = (int*)alloc((size_t)N_NODES * 4);
    int* in_deg    = (int*)alloc((size_t)N_NODES * 4);
    float* out_scale = (float*)alloc((size_t)N_NODES * 4);
    float* in_scale  = (float*)alloc((size_t)N_NODES * 4);
    int* csr_edge  = (int*)alloc((size_t)N_EDGES * 4);
    u16* wvfrag = (u16*)alloc((size_t)3 * 16384 * 2);         // w1|w2|v bf16 frags
    u16* hrow   = (u16*)alloc((size_t)N_NODES * 256 * 2);     // [sum|prod] per channel
    u16* hp     = (u16*)alloc((size_t)N_NODES * 128 * 2);

    (void)in_sizes; (void)n_in; (void)out_size; (void)ws_size;

    kA_count<<<NBLK + NB_PREPW, 256, 0, stream>>>(src, dst, countsD, countsS, w1, w2, v, wvfrag);
    kA_scan<<<2 * NBUK, 256, 0, stream>>>(countsD, countsS, totD, totS);
    kA_scatter<<<NBLK, 256, 0, stream>>>(src, dst, attr, countsD, countsS, totD, totS, dbuf, sbuf);
    k_build<<<2 * NBUK, 256, 0, stream>>>(dbuf, sbuf, totD, totS,
                                          csr_start, in_deg, in_scale, out_scale, csr_edge);
    k_gemm<<<(N_NODES + 63) / 64, 256, 0, stream>>>(feat, out_scale, wvfrag, w2, hrow);
    k_edge<<<2048, 256, 0, stream>>>(csr_start, in_deg, csr_edge, hrow, bond, out, hp);
    k_final<<<(N_NODES + 63) / 64, 256, 0, stream>>>(hp, wvfrag + 2 * 16384, in_scale, out);
}